// Round 1
// baseline (920.912 us; speedup 1.0000x reference)
//
#include <hip/hip_runtime.h>
#include <hip/hip_bf16.h>
#include <cstdint>
#include <cstddef>

#define NN 100000
#define NE 1600000
#define TAU 0.3f

// ---------------- weight prep: Bproj[k][j], j = w*128 + head*32 + d ----------------
__global__ __launch_bounds__(256) void prep_weights(
    const float* __restrict__ Wq, const float* __restrict__ Wk, const float* __restrict__ Wm,
    const float* __restrict__ bq, const float* __restrict__ bk, const float* __restrict__ bm,
    float* __restrict__ Bproj, float* __restrict__ bvec) {
  int id = blockIdx.x * 256 + threadIdx.x;
  if (id >= 128 * 384) return;
  int j = id % 384;
  int k = id / 384;
  int w = j >> 7, r = j & 127, hh = r >> 5, d = r & 31;
  const float* W = (w == 0) ? Wq : (w == 1) ? Wk : Wm;
  Bproj[id] = W[hh * 4096 + k * 32 + d];
  if (k == 0) {
    const float* bb = (w == 0) ? bq : (w == 1) ? bk : bm;
    bvec[j] = bb[hh * 32 + d];
  }
}

// ---------------- f32 GEMM: C[M x ldb] = A[M x 128] * B[128 x ldb] + bias ----------------
// block: 64 rows x 128 cols, 256 threads, thread = 4 rows (stride 16) x 8 cols
__global__ __launch_bounds__(256) void gemm128(
    const float* __restrict__ A, const float* __restrict__ B,
    const float* __restrict__ bias, float* __restrict__ C,
    int M, int ldb, int relu) {
  __shared__ __align__(16) float Bs[128][128];   // 64 KB
  __shared__ __align__(16) float As[64][132];    // ~33.8 KB, padded rows

  int t = threadIdx.x;
  int rowBase = blockIdx.x * 64;
  int colBase = blockIdx.y * 128;

  // stage B tile (128x128)
#pragma unroll
  for (int i = 0; i < 16; i++) {
    int flat = t + i * 256;          // 4096 float4 slots
    int k = flat >> 5;
    int c4 = flat & 31;
    *(float4*)&Bs[k][c4 * 4] = *(const float4*)&B[k * ldb + colBase + c4 * 4];
  }
  // stage A tile (64 rows x 128 k), row-major
#pragma unroll
  for (int i = 0; i < 8; i++) {
    int flat = t + i * 256;          // 2048 float4 slots
    int r = flat >> 5;
    int k4 = flat & 31;
    int row = rowBase + r;
    float4 v = make_float4(0.f, 0.f, 0.f, 0.f);
    if (row < M) v = *(const float4*)&A[(size_t)row * 128 + k4 * 4];
    *(float4*)&As[r][k4 * 4] = v;
  }
  __syncthreads();

  int tc = t & 15;        // col group
  int tr = t >> 4;        // row group (0..15), rows tr + {0,16,32,48}
  float acc[4][8];
#pragma unroll
  for (int i = 0; i < 4; i++)
#pragma unroll
    for (int j = 0; j < 8; j++) acc[i][j] = 0.f;

#pragma unroll 4
  for (int k = 0; k < 128; k++) {
    float av[4];
    av[0] = As[tr][k];
    av[1] = As[tr + 16][k];
    av[2] = As[tr + 32][k];
    av[3] = As[tr + 48][k];
    float4 b0 = *(const float4*)&Bs[k][tc * 4];
    float4 b1 = *(const float4*)&Bs[k][tc * 4 + 64];
    float bv[8] = {b0.x, b0.y, b0.z, b0.w, b1.x, b1.y, b1.z, b1.w};
#pragma unroll
    for (int i = 0; i < 4; i++)
#pragma unroll
      for (int j = 0; j < 8; j++)
        acc[i][j] = fmaf(av[i], bv[j], acc[i][j]);
  }

  float4 bb0 = *(const float4*)&bias[colBase + tc * 4];
  float4 bb1 = *(const float4*)&bias[colBase + tc * 4 + 64];
#pragma unroll
  for (int i = 0; i < 4; i++) {
    int row = rowBase + tr + i * 16;
    if (row >= M) continue;
    float4 o0 = make_float4(acc[i][0] + bb0.x, acc[i][1] + bb0.y,
                            acc[i][2] + bb0.z, acc[i][3] + bb0.w);
    float4 o1 = make_float4(acc[i][4] + bb1.x, acc[i][5] + bb1.y,
                            acc[i][6] + bb1.z, acc[i][7] + bb1.w);
    if (relu) {
      o0.x = fmaxf(o0.x, 0.f); o0.y = fmaxf(o0.y, 0.f);
      o0.z = fmaxf(o0.z, 0.f); o0.w = fmaxf(o0.w, 0.f);
      o1.x = fmaxf(o1.x, 0.f); o1.y = fmaxf(o1.y, 0.f);
      o1.z = fmaxf(o1.z, 0.f); o1.w = fmaxf(o1.w, 0.f);
    }
    *(float4*)&C[(size_t)row * ldb + colBase + tc * 4] = o0;
    *(float4*)&C[(size_t)row * ldb + colBase + tc * 4 + 64] = o1;
  }
}

// ---------------- edge logits: eexp[e][h] = exp(tau * dot32(zk[src],zq[dst])) ----------------
// 8 lanes per edge; lane j covers dims [j*16, j*16+16) -> head j>>1
__global__ __launch_bounds__(256) void edge_logits(
    const float* __restrict__ Z, const int* __restrict__ src, const int* __restrict__ dst,
    float* __restrict__ eexp, float* __restrict__ denom) {
  int t = threadIdx.x;
  int e = blockIdx.x * 32 + (t >> 3);
  if (e >= NE) return;
  int j = t & 7;
  int s = src[e], d = dst[e];
  const float4* zk = (const float4*)(Z + (size_t)s * 384 + 128);
  const float4* zq = (const float4*)(Z + (size_t)d * 384);
  float sum = 0.f;
#pragma unroll
  for (int i = 0; i < 4; i++) {
    float4 a = zk[j * 4 + i];
    float4 b = zq[j * 4 + i];
    sum += a.x * b.x + a.y * b.y + a.z * b.z + a.w * b.w;
  }
  sum += __shfl_xor(sum, 1);
  if ((j & 1) == 0) {
    float p = expf(TAU * sum);
    int hh = j >> 1;
    eexp[(size_t)e * 4 + hh] = p;
    atomicAdd(&denom[(size_t)d * 4 + hh], p);
  }
}

// ---------------- CSR build ----------------
__global__ __launch_bounds__(256) void hist_kernel(const int* __restrict__ dst, int* __restrict__ counts) {
  int e = blockIdx.x * 256 + threadIdx.x;
  if (e < NE) atomicAdd(&counts[dst[e]], 1);
}

__global__ __launch_bounds__(256) void scan_a(const int* __restrict__ counts,
                                              int* __restrict__ offsets,
                                              int* __restrict__ blockSums, int n) {
  __shared__ int lds[256];
  int b = blockIdx.x, t = threadIdx.x;
  int base = b * 1024 + t * 4;
  int4 v = make_int4(0, 0, 0, 0);
  if (base < n) v = *(const int4*)&counts[base];   // n % 4 == 0
  int s1 = v.x + v.y, s2 = s1 + v.z, s3 = s2 + v.w;
  lds[t] = s3;
  __syncthreads();
  for (int dd = 1; dd < 256; dd <<= 1) {
    int x = (t >= dd) ? lds[t - dd] : 0;
    __syncthreads();
    lds[t] += x;
    __syncthreads();
  }
  int excl = (t > 0) ? lds[t - 1] : 0;
  if (base < n) {
    int4 o = make_int4(excl, excl + v.x, excl + s1, excl + s2);
    *(int4*)&offsets[base] = o;
  }
  if (t == 255) blockSums[b] = lds[255];
}

__global__ __launch_bounds__(128) void scan_b(int* __restrict__ blockSums, int nb) {
  __shared__ int lds[128];
  int t = threadIdx.x;
  lds[t] = (t < nb) ? blockSums[t] : 0;
  __syncthreads();
  for (int dd = 1; dd < 128; dd <<= 1) {
    int x = (t >= dd) ? lds[t - dd] : 0;
    __syncthreads();
    lds[t] += x;
    __syncthreads();
  }
  if (t < nb) blockSums[t] = (t > 0) ? lds[t - 1] : 0;
}

__global__ __launch_bounds__(256) void scan_c(int* __restrict__ offsets,
                                              const int* __restrict__ blockSums,
                                              int* __restrict__ cursor, int n) {
  int i = blockIdx.x * 256 + threadIdx.x;
  if (i < n) {
    int v = offsets[i] + blockSums[i >> 10];
    offsets[i] = v;
    cursor[i] = v;
  }
  if (i == 0) offsets[n] = NE;
}

__global__ __launch_bounds__(256) void scatter_kernel(
    const int* __restrict__ src, const int* __restrict__ dst,
    int* __restrict__ cursor, int* __restrict__ csr_src, int* __restrict__ csr_eid) {
  int e = blockIdx.x * 256 + threadIdx.x;
  if (e >= NE) return;
  int d = dst[e];
  int pos = atomicAdd(&cursor[d], 1);
  csr_src[pos] = src[e];
  csr_eid[pos] = e;
}

// ---------------- per-node aggregation (wave per node, 2 dims/lane) ----------------
__global__ __launch_bounds__(256) void aggregate(
    const float* __restrict__ Z, const float* __restrict__ eexp,
    const float* __restrict__ denom, const int* __restrict__ offsets,
    const int* __restrict__ csr_src, const int* __restrict__ csr_eid,
    float* __restrict__ agg) {
  int wave = threadIdx.x >> 6;
  int lane = threadIdx.x & 63;
  int n = blockIdx.x * 4 + wave;
  if (n >= NN) return;
  int hh = lane >> 4;                 // head of dims (2*lane, 2*lane+1)
  float den = denom[n * 4 + hh];
  float inv = (den > 0.f) ? 1.0f / den : 1.0f;
  int start = offsets[n], end = offsets[n + 1];
  float a0 = 0.f, a1 = 0.f;
  for (int p = start; p < end; p++) {
    int sid = csr_src[p];
    int eid = csr_eid[p];
    float w = eexp[(size_t)eid * 4 + hh] * inv;
    float2 zm = *(const float2*)(Z + (size_t)sid * 384 + 256 + lane * 2);
    a0 = fmaf(zm.x, w, a0);
    a1 = fmaf(zm.y, w, a1);
  }
  float2 o = make_float2(a0, a1);
  *(float2*)&agg[(size_t)n * 128 + lane * 2] = o;
}

// ---------------- launch ----------------
extern "C" void kernel_launch(void* const* d_in, const int* in_sizes, int n_in,
                              void* d_out, int out_size, void* d_ws, size_t ws_size,
                              hipStream_t stream) {
  const float* h    = (const float*)d_in[0];
  const int*   src  = (const int*)d_in[1];
  const int*   dst  = (const int*)d_in[2];
  const float* Wq   = (const float*)d_in[3];
  const float* bq   = (const float*)d_in[4];
  const float* Wk   = (const float*)d_in[5];
  const float* bk   = (const float*)d_in[6];
  const float* Wm   = (const float*)d_in[7];
  const float* bm   = (const float*)d_in[8];
  const float* Wout = (const float*)d_in[9];
  const float* bout = (const float*)d_in[10];
  float* out = (float*)d_out;

  float* Z      = (float*)d_ws;                       // NN*384
  float* eexp   = Z + (size_t)NN * 384;               // NE*4
  float* agg    = eexp + (size_t)NE * 4;              // NN*128
  float* Bproj  = agg + (size_t)NN * 128;             // 128*384
  float* bvec   = Bproj + 128 * 384;                  // 384
  float* denom  = bvec + 384;                         // NN*4
  int* counts   = (int*)(denom + (size_t)NN * 4);     // NN
  int* offsets  = counts + NN;                        // NN+1
  int* cursor   = offsets + (NN + 1);                 // NN
  int* blockSums = cursor + NN;                       // 128
  int* csr_src  = blockSums + 128;                    // NE
  int* csr_eid  = csr_src + NE;                       // NE

  hipMemsetAsync(denom, 0, (size_t)NN * 4 * sizeof(float), stream);
  hipMemsetAsync(counts, 0, (size_t)NN * sizeof(int), stream);

  prep_weights<<<192, 256, 0, stream>>>(Wq, Wk, Wm, bq, bk, bm, Bproj, bvec);
  gemm128<<<dim3(1563, 3), 256, 0, stream>>>(h, Bproj, bvec, Z, NN, 384, 0);

  hist_kernel<<<6250, 256, 0, stream>>>(dst, counts);
  scan_a<<<98, 256, 0, stream>>>(counts, offsets, blockSums, NN);
  scan_b<<<1, 128, 0, stream>>>(blockSums, 98);
  scan_c<<<391, 256, 0, stream>>>(offsets, blockSums, cursor, NN);

  edge_logits<<<50000, 256, 0, stream>>>(Z, src, dst, eexp, denom);
  scatter_kernel<<<6250, 256, 0, stream>>>(src, dst, cursor, csr_src, csr_eid);
  aggregate<<<25000, 256, 0, stream>>>(Z, eexp, denom, offsets, csr_src, csr_eid, agg);

  gemm128<<<dim3(1563, 1), 256, 0, stream>>>(agg, Wout, bout, out, NN, 128, 1);
}

// Round 2
// 435.706 us; speedup vs baseline: 2.1136x; 2.1136x over previous
//
#include <hip/hip_runtime.h>
#include <hip/hip_bf16.h>
#include <cstdint>
#include <cstddef>

#define NN 100000
#define NE 1600000
#define TAU 0.3f

typedef __attribute__((ext_vector_type(8))) short bf16x8;
typedef __attribute__((ext_vector_type(4))) float f32x4;

static __device__ __forceinline__ float b2f(ushort u) {
  return __uint_as_float(((uint)u) << 16);
}
static __device__ __forceinline__ ushort f2b(float f) {
  uint x = __float_as_uint(f);
  return (ushort)((x + 0x7fffu + ((x >> 16) & 1u)) >> 16);
}

// ---------------- h (f32) -> Abf (bf16), 8 elems/thread ----------------
__global__ __launch_bounds__(256) void conv_h(const float* __restrict__ h,
                                              ushort* __restrict__ A) {
  int i = blockIdx.x * 256 + threadIdx.x;   // exactly 1.6M threads
  const float4* hv = (const float4*)h + (size_t)i * 2;
  float4 a = hv[0], b = hv[1];
  uint4 o;
  o.x = (uint)f2b(a.x) | ((uint)f2b(a.y) << 16);
  o.y = (uint)f2b(a.z) | ((uint)f2b(a.w) << 16);
  o.z = (uint)f2b(b.x) | ((uint)f2b(b.y) << 16);
  o.w = (uint)f2b(b.z) | ((uint)f2b(b.w) << 16);
  ((uint4*)A)[i] = o;
}

// ---------------- weight prep: BT layouts (col-major-by-row = B^T) ----------------
// BTproj[j][k], j = w*128 + head*32 + d (j in [0,384)), k in [0,128)
// BTout[c][k] = Wout[k][c]
__global__ __launch_bounds__(256) void prep(
    const float* __restrict__ Wq, const float* __restrict__ Wk, const float* __restrict__ Wm,
    const float* __restrict__ bq, const float* __restrict__ bk, const float* __restrict__ bm,
    const float* __restrict__ Wout,
    ushort* __restrict__ BTproj, ushort* __restrict__ BTout, float* __restrict__ bvec) {
  int id = blockIdx.x * 256 + threadIdx.x;   // 65536 threads
  if (id < 384 * 128) {
    int j = id >> 7, k = id & 127;
    int w = j >> 7, r = j & 127, hh = r >> 5, d = r & 31;
    const float* W = (w == 0) ? Wq : (w == 1) ? Wk : Wm;
    BTproj[id] = f2b(W[hh * 4096 + k * 32 + d]);
    if (k == 0) {
      const float* bb = (w == 0) ? bq : (w == 1) ? bk : bm;
      bvec[j] = bb[hh * 32 + d];
    }
  } else {
    int id2 = id - 384 * 128;                // 16384
    int c = id2 >> 7, k = id2 & 127;
    BTout[id2] = f2b(Wout[k * 128 + c]);
  }
}

// ---------------- MFMA GEMM: C[M][ncols] = A[M][128] * BT^T + bias ----------------
// A bf16 row-major [M][128], BT bf16 [ncols][128]. 128x128 tile, 4 waves of 64x64.
template <int RELU, int OUTBF>
__global__ __launch_bounds__(256) void mfma_gemm(
    const ushort* __restrict__ A, const ushort* __restrict__ BT,
    const float* __restrict__ bias, void* __restrict__ Cp, int M, int ncols) {
  __shared__ ushort As[128 * 128];   // 32 KB, XOR-swizzled rows
  __shared__ ushort Bs[128 * 128];   // 32 KB

  int t = threadIdx.x;
  int rowBase = blockIdx.x * 128, colBase = blockIdx.y * 128;

#pragma unroll
  for (int i = 0; i < 8; i++) {
    int flat = t + i * 256;          // 2048 chunks of 16B
    int row = flat >> 4;
    int kb = (flat & 15) * 16;       // byte offset along K
    int grow = rowBase + row;
    uint4 v = make_uint4(0, 0, 0, 0);
    if (grow < M) v = *(const uint4*)((const char*)A + (size_t)grow * 256 + kb);
    *(uint4*)((char*)As + row * 256 + (kb ^ ((row & 7) << 4))) = v;
    uint4 w = *(const uint4*)((const char*)BT + (size_t)(colBase + row) * 256 + kb);
    *(uint4*)((char*)Bs + row * 256 + (kb ^ ((row & 7) << 4))) = w;
  }
  __syncthreads();

  int wv = t >> 6, L = t & 63;
  int wrow = (wv >> 1) * 64, wcol = (wv & 1) * 64;
  int lr = L & 15;
  int lk = (L >> 4) * 16;            // byte offset of this lane's 8 bf16 within 64B k-step
  f32x4 acc[4][4] = {};

#pragma unroll
  for (int ks = 0; ks < 4; ks++) {
    bf16x8 a[4], b[4];
#pragma unroll
    for (int i = 0; i < 4; i++) {
      int row = wrow + i * 16 + lr;
      a[i] = *(const bf16x8*)((const char*)As + row * 256 + ((ks * 64 + lk) ^ ((row & 7) << 4)));
      int col = wcol + i * 16 + lr;
      b[i] = *(const bf16x8*)((const char*)Bs + col * 256 + ((ks * 64 + lk) ^ ((col & 7) << 4)));
    }
#pragma unroll
    for (int i = 0; i < 4; i++)
#pragma unroll
      for (int j = 0; j < 4; j++)
        acc[i][j] = __builtin_amdgcn_mfma_f32_16x16x32_bf16(a[i], b[j], acc[i][j], 0, 0, 0);
  }

  int rquad = (L >> 4) * 4;
#pragma unroll
  for (int j = 0; j < 4; j++) {
    int col = colBase + wcol + j * 16 + lr;
    float bs = bias[col];
#pragma unroll
    for (int i = 0; i < 4; i++) {
      int row0 = rowBase + wrow + i * 16 + rquad;
#pragma unroll
      for (int r = 0; r < 4; r++) {
        int row = row0 + r;
        if (row >= M) continue;
        float v = acc[i][j][r] + bs;
        if (RELU) v = fmaxf(v, 0.f);
        if (OUTBF) ((ushort*)Cp)[(size_t)row * ncols + col] = f2b(v);
        else       ((float*)Cp)[(size_t)row * ncols + col] = v;
      }
    }
  }
}

// ---------------- CSR build ----------------
__global__ __launch_bounds__(256) void hist_kernel(const int* __restrict__ dst,
                                                   int* __restrict__ counts) {
  int e = blockIdx.x * 256 + threadIdx.x;
  if (e < NE) atomicAdd(&counts[dst[e]], 1);
}

__global__ __launch_bounds__(256) void scan_a(const int* __restrict__ counts,
                                              int* __restrict__ offsets,
                                              int* __restrict__ blockSums, int n) {
  __shared__ int lds[256];
  int b = blockIdx.x, t = threadIdx.x;
  int base = b * 1024 + t * 4;
  int4 v = make_int4(0, 0, 0, 0);
  if (base < n) v = *(const int4*)&counts[base];
  int s1 = v.x + v.y, s2 = s1 + v.z, s3 = s2 + v.w;
  lds[t] = s3;
  __syncthreads();
  for (int dd = 1; dd < 256; dd <<= 1) {
    int x = (t >= dd) ? lds[t - dd] : 0;
    __syncthreads();
    lds[t] += x;
    __syncthreads();
  }
  int excl = (t > 0) ? lds[t - 1] : 0;
  if (base < n) {
    int4 o = make_int4(excl, excl + v.x, excl + s1, excl + s2);
    *(int4*)&offsets[base] = o;
  }
  if (t == 255) blockSums[b] = lds[255];
}

__global__ __launch_bounds__(128) void scan_b(int* __restrict__ blockSums, int nb) {
  __shared__ int lds[128];
  int t = threadIdx.x;
  lds[t] = (t < nb) ? blockSums[t] : 0;
  __syncthreads();
  for (int dd = 1; dd < 128; dd <<= 1) {
    int x = (t >= dd) ? lds[t - dd] : 0;
    __syncthreads();
    lds[t] += x;
    __syncthreads();
  }
  if (t < nb) blockSums[t] = (t > 0) ? lds[t - 1] : 0;
}

__global__ __launch_bounds__(256) void scan_c(int* __restrict__ offsets,
                                              const int* __restrict__ blockSums,
                                              int* __restrict__ cursor, int n) {
  int i = blockIdx.x * 256 + threadIdx.x;
  if (i < n) {
    int v = offsets[i] + blockSums[i >> 10];
    offsets[i] = v;
    cursor[i] = v;
  }
  if (i == 0) offsets[n] = NE;
}

__global__ __launch_bounds__(256) void scatter_kernel(
    const int* __restrict__ src, const int* __restrict__ dst,
    int* __restrict__ cursor, int* __restrict__ csr_src) {
  int e = blockIdx.x * 256 + threadIdx.x;
  if (e >= NE) return;
  int pos = atomicAdd(&cursor[dst[e]], 1);
  csr_src[pos] = src[e];
}

// ---------------- fused per-node attention + aggregation ----------------
// wave per node; lane: head hh = L>>4, dims dd=2*(L&15), dd+1.
// Z row layout (bf16): [zq 0..127 | zk 128..255 | zm 256..383]
__global__ __launch_bounds__(256) void aggregate_fused(
    const ushort* __restrict__ Z, const int* __restrict__ offsets,
    const int* __restrict__ csr_src, ushort* __restrict__ aggbf) {
  int wv = threadIdx.x >> 6, L = threadIdx.x & 63;
  int n = blockIdx.x * 4 + wv;
  if (n >= NN) return;
  int zoff = (L >> 4) * 32 + (L & 15) * 2;   // hh*32 + dd

  uint qw = *(const uint*)(Z + (size_t)n * 384 + zoff);
  float q0 = b2f((ushort)qw), q1 = b2f((ushort)(qw >> 16));

  int start = offsets[n], end = offsets[n + 1];
  float den = 0.f, a0 = 0.f, a1 = 0.f;
  int p = start;
  for (; p + 2 <= end; p += 2) {
    int s0 = csr_src[p], s1 = csr_src[p + 1];
    const ushort* r0 = Z + (size_t)s0 * 384;
    const ushort* r1 = Z + (size_t)s1 * 384;
    uint k0 = *(const uint*)(r0 + 128 + zoff);
    uint m0 = *(const uint*)(r0 + 256 + zoff);
    uint k1 = *(const uint*)(r1 + 128 + zoff);
    uint m1 = *(const uint*)(r1 + 256 + zoff);
    float pa = b2f((ushort)k0) * q0 + b2f((ushort)(k0 >> 16)) * q1;
    float pb = b2f((ushort)k1) * q0 + b2f((ushort)(k1 >> 16)) * q1;
    pa += __shfl_xor(pa, 1); pa += __shfl_xor(pa, 2);
    pa += __shfl_xor(pa, 4); pa += __shfl_xor(pa, 8);
    pb += __shfl_xor(pb, 1); pb += __shfl_xor(pb, 2);
    pb += __shfl_xor(pb, 4); pb += __shfl_xor(pb, 8);
    float w0 = __expf(TAU * pa), w1 = __expf(TAU * pb);
    den += w0 + w1;
    a0 = fmaf(b2f((ushort)m0), w0, a0); a1 = fmaf(b2f((ushort)(m0 >> 16)), w0, a1);
    a0 = fmaf(b2f((ushort)m1), w1, a0); a1 = fmaf(b2f((ushort)(m1 >> 16)), w1, a1);
  }
  if (p < end) {
    int s0 = csr_src[p];
    const ushort* r0 = Z + (size_t)s0 * 384;
    uint k0 = *(const uint*)(r0 + 128 + zoff);
    uint m0 = *(const uint*)(r0 + 256 + zoff);
    float pa = b2f((ushort)k0) * q0 + b2f((ushort)(k0 >> 16)) * q1;
    pa += __shfl_xor(pa, 1); pa += __shfl_xor(pa, 2);
    pa += __shfl_xor(pa, 4); pa += __shfl_xor(pa, 8);
    float w0 = __expf(TAU * pa);
    den += w0;
    a0 = fmaf(b2f((ushort)m0), w0, a0); a1 = fmaf(b2f((ushort)(m0 >> 16)), w0, a1);
  }
  float inv = (den > 0.f) ? 1.0f / den : 0.f;
  uint o = (uint)f2b(a0 * inv) | ((uint)f2b(a1 * inv) << 16);
  *(uint*)(aggbf + (size_t)n * 128 + zoff) = o;
}

// ---------------- launch ----------------
extern "C" void kernel_launch(void* const* d_in, const int* in_sizes, int n_in,
                              void* d_out, int out_size, void* d_ws, size_t ws_size,
                              hipStream_t stream) {
  const float* h    = (const float*)d_in[0];
  const int*   src  = (const int*)d_in[1];
  const int*   dst  = (const int*)d_in[2];
  const float* Wq   = (const float*)d_in[3];
  const float* bq   = (const float*)d_in[4];
  const float* Wk   = (const float*)d_in[5];
  const float* bk   = (const float*)d_in[6];
  const float* Wm   = (const float*)d_in[7];
  const float* bm   = (const float*)d_in[8];
  const float* Wout = (const float*)d_in[9];
  const float* bout = (const float*)d_in[10];
  float* out = (float*)d_out;

  ushort* Abf    = (ushort*)d_ws;                    // NN*128 bf16
  ushort* Zbf    = Abf + (size_t)NN * 128;           // NN*384 bf16
  ushort* aggbf  = Zbf + (size_t)NN * 384;           // NN*128 bf16
  ushort* BTproj = aggbf + (size_t)NN * 128;         // 384*128
  ushort* BTout  = BTproj + 384 * 128;               // 128*128
  float*  bvec   = (float*)(BTout + 128 * 128);      // 384
  int* counts    = (int*)(bvec + 384);               // NN
  int* offsets   = counts + NN;                      // NN+1
  int* cursor    = offsets + NN + 1;                 // NN
  int* blockSums = cursor + NN;                      // 128
  int* csr_src   = blockSums + 128;                  // NE

  hipMemsetAsync(counts, 0, (size_t)NN * sizeof(int), stream);

  conv_h<<<6250, 256, 0, stream>>>(h, Abf);
  prep<<<256, 256, 0, stream>>>(Wq, Wk, Wm, bq, bk, bm, Wout, BTproj, BTout, bvec);
  mfma_gemm<0, 1><<<dim3(782, 3), 256, 0, stream>>>(Abf, BTproj, bvec, Zbf, NN, 384);

  hist_kernel<<<6250, 256, 0, stream>>>(dst, counts);
  scan_a<<<98, 256, 0, stream>>>(counts, offsets, blockSums, NN);
  scan_b<<<1, 128, 0, stream>>>(blockSums, 98);
  scan_c<<<391, 256, 0, stream>>>(offsets, blockSums, cursor, NN);
  scatter_kernel<<<6250, 256, 0, stream>>>(src, dst, cursor, csr_src);

  aggregate_fused<<<25000, 256, 0, stream>>>(Zbf, offsets, csr_src, aggbf);

  mfma_gemm<1, 0><<<dim3(782, 1), 256, 0, stream>>>(aggbf, BTout, bout, out, NN, 128);
}

// Round 3
// 415.071 us; speedup vs baseline: 2.2187x; 1.0497x over previous
//
#include <hip/hip_runtime.h>
#include <hip/hip_bf16.h>
#include <cstdint>
#include <cstddef>

#define NN 100000
#define NE 1600000
#define TAU 0.3f

typedef __attribute__((ext_vector_type(8))) short bf16x8;
typedef __attribute__((ext_vector_type(4))) float f32x4;

static __device__ __forceinline__ float b2f(ushort u) {
  return __uint_as_float(((uint)u) << 16);
}
static __device__ __forceinline__ float b2f_hi(uint w) {
  return __uint_as_float(w & 0xffff0000u);
}
static __device__ __forceinline__ float b2f_lo(uint w) {
  return __uint_as_float(w << 16);
}
static __device__ __forceinline__ ushort f2b(float f) {
  uint x = __float_as_uint(f);
  return (ushort)((x + 0x7fffu + ((x >> 16) & 1u)) >> 16);
}

// ---------------- h (f32) -> Abf (bf16), 8 elems/thread ----------------
__global__ __launch_bounds__(256) void conv_h(const float* __restrict__ h,
                                              ushort* __restrict__ A) {
  int i = blockIdx.x * 256 + threadIdx.x;   // exactly 1.6M threads
  const float4* hv = (const float4*)h + (size_t)i * 2;
  float4 a = hv[0], b = hv[1];
  uint4 o;
  o.x = (uint)f2b(a.x) | ((uint)f2b(a.y) << 16);
  o.y = (uint)f2b(a.z) | ((uint)f2b(a.w) << 16);
  o.z = (uint)f2b(b.x) | ((uint)f2b(b.y) << 16);
  o.w = (uint)f2b(b.z) | ((uint)f2b(b.w) << 16);
  ((uint4*)A)[i] = o;
}

// ---------------- weight prep ----------------
__global__ __launch_bounds__(256) void prep(
    const float* __restrict__ Wq, const float* __restrict__ Wk, const float* __restrict__ Wm,
    const float* __restrict__ bq, const float* __restrict__ bk, const float* __restrict__ bm,
    const float* __restrict__ Wout,
    ushort* __restrict__ BTproj, ushort* __restrict__ BTout, float* __restrict__ bvec) {
  int id = blockIdx.x * 256 + threadIdx.x;   // 65536 threads
  if (id < 384 * 128) {
    int j = id >> 7, k = id & 127;
    int w = j >> 7, r = j & 127, hh = r >> 5, d = r & 31;
    const float* W = (w == 0) ? Wq : (w == 1) ? Wk : Wm;
    BTproj[id] = f2b(W[hh * 4096 + k * 32 + d]);
    if (k == 0) {
      const float* bb = (w == 0) ? bq : (w == 1) ? bk : bm;
      bvec[j] = bb[hh * 32 + d];
    }
  } else {
    int id2 = id - 384 * 128;                // 16384
    int c = id2 >> 7, k = id2 & 127;
    BTout[id2] = f2b(Wout[k * 128 + c]);
  }
}

// ---------------- MFMA GEMM: C[M][ncols] = A[M][128] * BT^T + bias ----------------
// A bf16 row-major [M][128], BT bf16 [ncols][128]. 128x128 tile, 4 waves of 64x64.
// Staging: global_load_lds width-16, linear LDS dest, pre-swizzled SOURCE addr (G21).
template <int RELU, int OUTBF>
__global__ __launch_bounds__(256) void mfma_gemm(
    const ushort* __restrict__ A, const ushort* __restrict__ BT,
    const float* __restrict__ bias, void* __restrict__ Cp, int M, int ncols) {
  __shared__ ushort As[128 * 128];   // 32 KB
  __shared__ ushort Bs[128 * 128];   // 32 KB

  int t = threadIdx.x;
  int rowBase = blockIdx.x * 128, colBase = blockIdx.y * 128;

#pragma unroll
  for (int i = 0; i < 8; i++) {
    int flat = t + i * 256;          // 2048 chunks of 16B
    int row = flat >> 4;
    int kb = (flat & 15) * 16;       // byte offset along K
    int soff = kb ^ ((row & 7) << 4);   // pre-swizzled source offset
    int ar = rowBase + row; if (ar >= M) ar = M - 1;   // clamp (results discarded)
    __builtin_amdgcn_global_load_lds(
        (const __attribute__((address_space(1))) uint32_t*)((const char*)A + (size_t)ar * 256 + soff),
        (__attribute__((address_space(3))) uint32_t*)((char*)As + row * 256 + kb), 16, 0, 0);
    __builtin_amdgcn_global_load_lds(
        (const __attribute__((address_space(1))) uint32_t*)((const char*)BT + (size_t)(colBase + row) * 256 + soff),
        (__attribute__((address_space(3))) uint32_t*)((char*)Bs + row * 256 + kb), 16, 0, 0);
  }
  __syncthreads();

  int wv = t >> 6, L = t & 63;
  int wrow = (wv >> 1) * 64, wcol = (wv & 1) * 64;
  int lr = L & 15;
  int lk = (L >> 4) * 16;            // byte offset of this lane's 8 bf16 within 64B k-step
  f32x4 acc[4][4] = {};

#pragma unroll
  for (int ks = 0; ks < 4; ks++) {
    bf16x8 a[4], b[4];
#pragma unroll
    for (int i = 0; i < 4; i++) {
      int row = wrow + i * 16 + lr;
      a[i] = *(const bf16x8*)((const char*)As + row * 256 + ((ks * 64 + lk) ^ ((row & 7) << 4)));
      int col = wcol + i * 16 + lr;
      b[i] = *(const bf16x8*)((const char*)Bs + col * 256 + ((ks * 64 + lk) ^ ((col & 7) << 4)));
    }
#pragma unroll
    for (int i = 0; i < 4; i++)
#pragma unroll
      for (int j = 0; j < 4; j++)
        acc[i][j] = __builtin_amdgcn_mfma_f32_16x16x32_bf16(a[i], b[j], acc[i][j], 0, 0, 0);
  }

  int rquad = (L >> 4) * 4;
#pragma unroll
  for (int j = 0; j < 4; j++) {
    int col = colBase + wcol + j * 16 + lr;
    float bs = bias[col];
#pragma unroll
    for (int i = 0; i < 4; i++) {
      int row0 = rowBase + wrow + i * 16 + rquad;
#pragma unroll
      for (int r = 0; r < 4; r++) {
        int row = row0 + r;
        if (row >= M) continue;
        float v = acc[i][j][r] + bs;
        if (RELU) v = fmaxf(v, 0.f);
        if (OUTBF) ((ushort*)Cp)[(size_t)row * ncols + col] = f2b(v);
        else       ((float*)Cp)[(size_t)row * ncols + col] = v;
      }
    }
  }
}

// ---------------- CSR build ----------------
__global__ __launch_bounds__(256) void hist_kernel(const int* __restrict__ dst,
                                                   int* __restrict__ counts) {
  int e = blockIdx.x * 256 + threadIdx.x;
  if (e < NE) atomicAdd(&counts[dst[e]], 1);
}

__global__ __launch_bounds__(256) void scan_a(const int* __restrict__ counts,
                                              int* __restrict__ offsets,
                                              int* __restrict__ blockSums, int n) {
  __shared__ int lds[256];
  int b = blockIdx.x, t = threadIdx.x;
  int base = b * 1024 + t * 4;
  int4 v = make_int4(0, 0, 0, 0);
  if (base < n) v = *(const int4*)&counts[base];
  int s1 = v.x + v.y, s2 = s1 + v.z, s3 = s2 + v.w;
  lds[t] = s3;
  __syncthreads();
  for (int dd = 1; dd < 256; dd <<= 1) {
    int x = (t >= dd) ? lds[t - dd] : 0;
    __syncthreads();
    lds[t] += x;
    __syncthreads();
  }
  int excl = (t > 0) ? lds[t - 1] : 0;
  if (base < n) {
    int4 o = make_int4(excl, excl + v.x, excl + s1, excl + s2);
    *(int4*)&offsets[base] = o;
  }
  if (t == 255) blockSums[b] = lds[255];
}

__global__ __launch_bounds__(128) void scan_b(int* __restrict__ blockSums, int nb) {
  __shared__ int lds[128];
  int t = threadIdx.x;
  lds[t] = (t < nb) ? blockSums[t] : 0;
  __syncthreads();
  for (int dd = 1; dd < 128; dd <<= 1) {
    int x = (t >= dd) ? lds[t - dd] : 0;
    __syncthreads();
    lds[t] += x;
    __syncthreads();
  }
  if (t < nb) blockSums[t] = (t > 0) ? lds[t - 1] : 0;
}

__global__ __launch_bounds__(256) void scan_c(int* __restrict__ offsets,
                                              const int* __restrict__ blockSums,
                                              int* __restrict__ cursor, int n) {
  int i = blockIdx.x * 256 + threadIdx.x;
  if (i < n) {
    int v = offsets[i] + blockSums[i >> 10];
    offsets[i] = v;
    cursor[i] = v;
  }
  if (i == 0) offsets[n] = NE;
}

// csr payload = src row BYTE offset (src*768)
__global__ __launch_bounds__(256) void scatter_kernel(
    const int* __restrict__ src, const int* __restrict__ dst,
    int* __restrict__ cursor, int* __restrict__ csr_off) {
  int e = blockIdx.x * 256 + threadIdx.x;
  if (e >= NE) return;
  int pos = atomicAdd(&cursor[dst[e]], 1);
  csr_off[pos] = src[e] * 768;
}

// ---------------- fused per-node attention + aggregation ----------------
// wave per node; lane: head hh = L>>4, dims dd=2*(L&15), dd+1.
// Z row layout (bf16): [zq 0..127 | zk 128..255 | zm 256..383], 768 B/row
__global__ __launch_bounds__(256) void aggregate_fused(
    const ushort* __restrict__ Z, const int* __restrict__ offsets,
    const int* __restrict__ csr_off, ushort* __restrict__ aggbf) {
  int wv = threadIdx.x >> 6, L = threadIdx.x & 63;
  int n = blockIdx.x * 4 + wv;
  if (n >= NN) return;
  int zoffb = ((L >> 4) * 32 + (L & 15) * 2) * 2;  // lane byte offset within 256B segment
  const char* ZB = (const char*)Z;
  int koff = 256 + zoffb;                           // zk segment

  uint qw = *(const uint*)(ZB + (size_t)n * 768 + zoffb);
  float q0 = b2f_lo(qw), q1 = b2f_hi(qw);

  int start = offsets[n], end = offsets[n + 1];
  float den = 0.f, a0 = 0.f, a1 = 0.f;
  int p = start;

  for (; p + 4 <= end; p += 4) {
    int adr[4];
#pragma unroll
    for (int j = 0; j < 4; j++) adr[j] = csr_off[p + j] + koff;
    uint kw[4], mw[4];
#pragma unroll
    for (int j = 0; j < 4; j++) {
      kw[j] = *(const uint*)(ZB + adr[j]);
      mw[j] = *(const uint*)(ZB + adr[j] + 256);
    }
    float pd[4];
#pragma unroll
    for (int j = 0; j < 4; j++)
      pd[j] = fmaf(b2f_lo(kw[j]), q0, b2f_hi(kw[j]) * q1);
#pragma unroll
    for (int j = 0; j < 4; j++) pd[j] += __shfl_xor(pd[j], 1);
#pragma unroll
    for (int j = 0; j < 4; j++) pd[j] += __shfl_xor(pd[j], 2);
#pragma unroll
    for (int j = 0; j < 4; j++) pd[j] += __shfl_xor(pd[j], 4);
#pragma unroll
    for (int j = 0; j < 4; j++) pd[j] += __shfl_xor(pd[j], 8);
#pragma unroll
    for (int j = 0; j < 4; j++) {
      float w = __expf(TAU * pd[j]);
      den += w;
      a0 = fmaf(b2f_lo(mw[j]), w, a0);
      a1 = fmaf(b2f_hi(mw[j]), w, a1);
    }
  }
  for (; p < end; p++) {
    int adr = csr_off[p] + koff;
    uint kw = *(const uint*)(ZB + adr);
    uint mw = *(const uint*)(ZB + adr + 256);
    float pa = fmaf(b2f_lo(kw), q0, b2f_hi(kw) * q1);
    pa += __shfl_xor(pa, 1); pa += __shfl_xor(pa, 2);
    pa += __shfl_xor(pa, 4); pa += __shfl_xor(pa, 8);
    float w = __expf(TAU * pa);
    den += w;
    a0 = fmaf(b2f_lo(mw), w, a0);
    a1 = fmaf(b2f_hi(mw), w, a1);
  }
  float inv = (den > 0.f) ? 1.0f / den : 0.f;
  uint o = (uint)f2b(a0 * inv) | ((uint)f2b(a1 * inv) << 16);
  *(uint*)((char*)aggbf + (size_t)n * 256 + zoffb) = o;
}

// ---------------- launch ----------------
extern "C" void kernel_launch(void* const* d_in, const int* in_sizes, int n_in,
                              void* d_out, int out_size, void* d_ws, size_t ws_size,
                              hipStream_t stream) {
  const float* h    = (const float*)d_in[0];
  const int*   src  = (const int*)d_in[1];
  const int*   dst  = (const int*)d_in[2];
  const float* Wq   = (const float*)d_in[3];
  const float* bq   = (const float*)d_in[4];
  const float* Wk   = (const float*)d_in[5];
  const float* bk   = (const float*)d_in[6];
  const float* Wm   = (const float*)d_in[7];
  const float* bm   = (const float*)d_in[8];
  const float* Wout = (const float*)d_in[9];
  const float* bout = (const float*)d_in[10];
  float* out = (float*)d_out;

  ushort* Abf    = (ushort*)d_ws;                    // NN*128 bf16
  ushort* Zbf    = Abf + (size_t)NN * 128;           // NN*384 bf16
  ushort* aggbf  = Zbf + (size_t)NN * 384;           // NN*128 bf16
  ushort* BTproj = aggbf + (size_t)NN * 128;         // 384*128
  ushort* BTout  = BTproj + 384 * 128;               // 128*128
  float*  bvec   = (float*)(BTout + 128 * 128);      // 384
  int* counts    = (int*)(bvec + 384);               // NN
  int* offsets   = counts + NN;                      // NN+1
  int* cursor    = offsets + NN + 1;                 // NN
  int* blockSums = cursor + NN;                      // 128
  int* csr_off   = blockSums + 128;                  // NE

  hipMemsetAsync(counts, 0, (size_t)NN * sizeof(int), stream);

  conv_h<<<6250, 256, 0, stream>>>(h, Abf);
  prep<<<256, 256, 0, stream>>>(Wq, Wk, Wm, bq, bk, bm, Wout, BTproj, BTout, bvec);
  mfma_gemm<0, 1><<<dim3(782, 3), 256, 0, stream>>>(Abf, BTproj, bvec, Zbf, NN, 384);

  hist_kernel<<<6250, 256, 0, stream>>>(dst, counts);
  scan_a<<<98, 256, 0, stream>>>(counts, offsets, blockSums, NN);
  scan_b<<<1, 128, 0, stream>>>(blockSums, 98);
  scan_c<<<391, 256, 0, stream>>>(offsets, blockSums, cursor, NN);
  scatter_kernel<<<6250, 256, 0, stream>>>(src, dst, cursor, csr_off);

  aggregate_fused<<<25000, 256, 0, stream>>>(Zbf, offsets, csr_off, aggbf);

  mfma_gemm<1, 0><<<dim3(782, 1), 256, 0, stream>>>(aggbf, BTout, bout, out, NN, 128);
}

// Round 4
// 373.508 us; speedup vs baseline: 2.4656x; 1.1113x over previous
//
#include <hip/hip_runtime.h>
#include <hip/hip_bf16.h>
#include <cstdint>
#include <cstddef>

#define NN 100000
#define NE 1600000
#define TAU 0.3f

typedef __attribute__((ext_vector_type(8))) short bf16x8;
typedef __attribute__((ext_vector_type(4))) float f32x4;

static __device__ __forceinline__ float b2f(ushort u) {
  return __uint_as_float(((uint)u) << 16);
}
static __device__ __forceinline__ float b2f_hi(uint w) {
  return __uint_as_float(w & 0xffff0000u);
}
static __device__ __forceinline__ float b2f_lo(uint w) {
  return __uint_as_float(w << 16);
}
static __device__ __forceinline__ ushort f2b(float f) {
  uint x = __float_as_uint(f);
  return (ushort)((x + 0x7fffu + ((x >> 16) & 1u)) >> 16);
}

// ---------------- h (f32) -> Abf (bf16), 8 elems/thread ----------------
__global__ __launch_bounds__(256) void conv_h(const float* __restrict__ h,
                                              ushort* __restrict__ A) {
  int i = blockIdx.x * 256 + threadIdx.x;   // exactly 1.6M threads
  const float4* hv = (const float4*)h + (size_t)i * 2;
  float4 a = hv[0], b = hv[1];
  uint4 o;
  o.x = (uint)f2b(a.x) | ((uint)f2b(a.y) << 16);
  o.y = (uint)f2b(a.z) | ((uint)f2b(a.w) << 16);
  o.z = (uint)f2b(b.x) | ((uint)f2b(b.y) << 16);
  o.w = (uint)f2b(b.z) | ((uint)f2b(b.w) << 16);
  ((uint4*)A)[i] = o;
}

// ---------------- weight prep ----------------
__global__ __launch_bounds__(256) void prep(
    const float* __restrict__ Wq, const float* __restrict__ Wk, const float* __restrict__ Wm,
    const float* __restrict__ bq, const float* __restrict__ bk, const float* __restrict__ bm,
    const float* __restrict__ Wout,
    ushort* __restrict__ BTproj, ushort* __restrict__ BTout, float* __restrict__ bvec) {
  int id = blockIdx.x * 256 + threadIdx.x;   // 65536 threads
  if (id < 384 * 128) {
    int j = id >> 7, k = id & 127;
    int w = j >> 7, r = j & 127, hh = r >> 5, d = r & 31;
    const float* W = (w == 0) ? Wq : (w == 1) ? Wk : Wm;
    BTproj[id] = f2b(W[hh * 4096 + k * 32 + d]);
    if (k == 0) {
      const float* bb = (w == 0) ? bq : (w == 1) ? bk : bm;
      bvec[j] = bb[hh * 32 + d];
    }
  } else {
    int id2 = id - 384 * 128;                // 16384
    int c = id2 >> 7, k = id2 & 127;
    BTout[id2] = f2b(Wout[k * 128 + c]);
  }
}

// ---------------- MFMA GEMM: C[M][ncols] = A[M][128] * BT^T + bias ----------------
// A bf16 row-major [M][128], BT bf16 [ncols][128]. 128x128 tile, 4 waves of 64x64.
// Staging: global_load_lds width-16, linear LDS dest, pre-swizzled SOURCE addr (G21).
template <int RELU, int OUTBF>
__global__ __launch_bounds__(256) void mfma_gemm(
    const ushort* __restrict__ A, const ushort* __restrict__ BT,
    const float* __restrict__ bias, void* __restrict__ Cp, int M, int ncols) {
  __shared__ ushort As[128 * 128];   // 32 KB
  __shared__ ushort Bs[128 * 128];   // 32 KB

  int t = threadIdx.x;
  int rowBase = blockIdx.x * 128, colBase = blockIdx.y * 128;

#pragma unroll
  for (int i = 0; i < 8; i++) {
    int flat = t + i * 256;          // 2048 chunks of 16B
    int row = flat >> 4;
    int kb = (flat & 15) * 16;       // byte offset along K
    int soff = kb ^ ((row & 7) << 4);   // pre-swizzled source offset
    int ar = rowBase + row; if (ar >= M) ar = M - 1;   // clamp (results discarded)
    __builtin_amdgcn_global_load_lds(
        (const __attribute__((address_space(1))) uint32_t*)((const char*)A + (size_t)ar * 256 + soff),
        (__attribute__((address_space(3))) uint32_t*)((char*)As + row * 256 + kb), 16, 0, 0);
    __builtin_amdgcn_global_load_lds(
        (const __attribute__((address_space(1))) uint32_t*)((const char*)BT + (size_t)(colBase + row) * 256 + soff),
        (__attribute__((address_space(3))) uint32_t*)((char*)Bs + row * 256 + kb), 16, 0, 0);
  }
  __syncthreads();

  int wv = t >> 6, L = t & 63;
  int wrow = (wv >> 1) * 64, wcol = (wv & 1) * 64;
  int lr = L & 15;
  int lk = (L >> 4) * 16;            // byte offset of this lane's 8 bf16 within 64B k-step
  f32x4 acc[4][4] = {};

#pragma unroll
  for (int ks = 0; ks < 4; ks++) {
    bf16x8 a[4], b[4];
#pragma unroll
    for (int i = 0; i < 4; i++) {
      int row = wrow + i * 16 + lr;
      a[i] = *(const bf16x8*)((const char*)As + row * 256 + ((ks * 64 + lk) ^ ((row & 7) << 4)));
      int col = wcol + i * 16 + lr;
      b[i] = *(const bf16x8*)((const char*)Bs + col * 256 + ((ks * 64 + lk) ^ ((col & 7) << 4)));
    }
#pragma unroll
    for (int i = 0; i < 4; i++)
#pragma unroll
      for (int j = 0; j < 4; j++)
        acc[i][j] = __builtin_amdgcn_mfma_f32_16x16x32_bf16(a[i], b[j], acc[i][j], 0, 0, 0);
  }

  int rquad = (L >> 4) * 4;
#pragma unroll
  for (int j = 0; j < 4; j++) {
    int col = colBase + wcol + j * 16 + lr;
    float bs = bias[col];
#pragma unroll
    for (int i = 0; i < 4; i++) {
      int row0 = rowBase + wrow + i * 16 + rquad;
#pragma unroll
      for (int r = 0; r < 4; r++) {
        int row = row0 + r;
        if (row >= M) continue;
        float v = acc[i][j][r] + bs;
        if (RELU) v = fmaxf(v, 0.f);
        if (OUTBF) ((ushort*)Cp)[(size_t)row * ncols + col] = f2b(v);
        else       ((float*)Cp)[(size_t)row * ncols + col] = v;
      }
    }
  }
}

// ---------------- CSR build ----------------
__global__ __launch_bounds__(256) void hist_kernel(const int* __restrict__ dst,
                                                   int* __restrict__ counts) {
  int e = blockIdx.x * 256 + threadIdx.x;
  if (e < NE) atomicAdd(&counts[dst[e]], 1);
}

__global__ __launch_bounds__(256) void scan_a(const int* __restrict__ counts,
                                              int* __restrict__ offsets,
                                              int* __restrict__ blockSums, int n) {
  __shared__ int lds[256];
  int b = blockIdx.x, t = threadIdx.x;
  int base = b * 1024 + t * 4;
  int4 v = make_int4(0, 0, 0, 0);
  if (base < n) v = *(const int4*)&counts[base];
  int s1 = v.x + v.y, s2 = s1 + v.z, s3 = s2 + v.w;
  lds[t] = s3;
  __syncthreads();
  for (int dd = 1; dd < 256; dd <<= 1) {
    int x = (t >= dd) ? lds[t - dd] : 0;
    __syncthreads();
    lds[t] += x;
    __syncthreads();
  }
  int excl = (t > 0) ? lds[t - 1] : 0;
  if (base < n) {
    int4 o = make_int4(excl, excl + v.x, excl + s1, excl + s2);
    *(int4*)&offsets[base] = o;
  }
  if (t == 255) blockSums[b] = lds[255];
}

__global__ __launch_bounds__(128) void scan_b(int* __restrict__ blockSums, int nb) {
  __shared__ int lds[128];
  int t = threadIdx.x;
  lds[t] = (t < nb) ? blockSums[t] : 0;
  __syncthreads();
  for (int dd = 1; dd < 128; dd <<= 1) {
    int x = (t >= dd) ? lds[t - dd] : 0;
    __syncthreads();
    lds[t] += x;
    __syncthreads();
  }
  if (t < nb) blockSums[t] = (t > 0) ? lds[t - 1] : 0;
}

__global__ __launch_bounds__(256) void scan_c(int* __restrict__ offsets,
                                              const int* __restrict__ blockSums,
                                              int* __restrict__ cursor, int n) {
  int i = blockIdx.x * 256 + threadIdx.x;
  if (i < n) {
    int v = offsets[i] + blockSums[i >> 10];
    offsets[i] = v;
    cursor[i] = v;
  }
  if (i == 0) offsets[n] = NE;
}

// ---- XCD-partitioned scatter: csr payload = src row BYTE offset (src*768) ----
// Partition p = dst >> 14 (7 live partitions, ~1 MB of CSR each — fits one L2).
// blockIdx % 8 selects partition; dispatch round-robin puts all writers of one
// CSR sub-region on one XCD -> 64B-line write merging in its private L2.
#define SC_CHUNK 4096
__global__ __launch_bounds__(256) void scatter_part(
    const int* __restrict__ src, const int* __restrict__ dst,
    int* __restrict__ cursor, int* __restrict__ csr_off) {
  int part = blockIdx.x & 7;
  int base = (blockIdx.x >> 3) * SC_CHUNK + threadIdx.x;
#pragma unroll
  for (int i = 0; i < SC_CHUNK / 256; i++) {
    int e = base + i * 256;
    if (e < NE) {
      int d = dst[e];
      if ((d >> 14) == part) {
        int pos = atomicAdd(&cursor[d], 1);
        csr_off[pos] = src[e] * 768;
      }
    }
  }
}

// ---------------- fused per-node attention + aggregation ----------------
// wave per node; lane: head hh = L>>4, dims dd=2*(L&15), dd+1.
// Z row layout (bf16): [zq 0..127 | zk 128..255 | zm 256..383], 768 B/row
__global__ __launch_bounds__(256) void aggregate_fused(
    const ushort* __restrict__ Z, const int* __restrict__ offsets,
    const int* __restrict__ csr_off, ushort* __restrict__ aggbf) {
  int wv = threadIdx.x >> 6, L = threadIdx.x & 63;
  int n = blockIdx.x * 4 + wv;
  if (n >= NN) return;
  int zoffb = ((L >> 4) * 32 + (L & 15) * 2) * 2;  // lane byte offset within 256B segment
  const char* ZB = (const char*)Z;
  int koff = 256 + zoffb;                           // zk segment

  uint qw = *(const uint*)(ZB + (size_t)n * 768 + zoffb);
  float q0 = b2f_lo(qw), q1 = b2f_hi(qw);

  int start = offsets[n], end = offsets[n + 1];
  float den = 0.f, a0 = 0.f, a1 = 0.f;
  int p = start;

  for (; p + 4 <= end; p += 4) {
    int adr[4];
#pragma unroll
    for (int j = 0; j < 4; j++) adr[j] = csr_off[p + j] + koff;
    uint kw[4], mw[4];
#pragma unroll
    for (int j = 0; j < 4; j++) {
      kw[j] = *(const uint*)(ZB + adr[j]);
      mw[j] = *(const uint*)(ZB + adr[j] + 256);
    }
    float pd[4];
#pragma unroll
    for (int j = 0; j < 4; j++)
      pd[j] = fmaf(b2f_lo(kw[j]), q0, b2f_hi(kw[j]) * q1);
#pragma unroll
    for (int j = 0; j < 4; j++) pd[j] += __shfl_xor(pd[j], 1);
#pragma unroll
    for (int j = 0; j < 4; j++) pd[j] += __shfl_xor(pd[j], 2);
#pragma unroll
    for (int j = 0; j < 4; j++) pd[j] += __shfl_xor(pd[j], 4);
#pragma unroll
    for (int j = 0; j < 4; j++) pd[j] += __shfl_xor(pd[j], 8);
#pragma unroll
    for (int j = 0; j < 4; j++) {
      float w = __expf(TAU * pd[j]);
      den += w;
      a0 = fmaf(b2f_lo(mw[j]), w, a0);
      a1 = fmaf(b2f_hi(mw[j]), w, a1);
    }
  }
  for (; p < end; p++) {
    int adr = csr_off[p] + koff;
    uint kw = *(const uint*)(ZB + adr);
    uint mw = *(const uint*)(ZB + adr + 256);
    float pa = fmaf(b2f_lo(kw), q0, b2f_hi(kw) * q1);
    pa += __shfl_xor(pa, 1); pa += __shfl_xor(pa, 2);
    pa += __shfl_xor(pa, 4); pa += __shfl_xor(pa, 8);
    float w = __expf(TAU * pa);
    den += w;
    a0 = fmaf(b2f_lo(mw), w, a0);
    a1 = fmaf(b2f_hi(mw), w, a1);
  }
  float inv = (den > 0.f) ? 1.0f / den : 0.f;
  uint o = (uint)f2b(a0 * inv) | ((uint)f2b(a1 * inv) << 16);
  *(uint*)((char*)aggbf + (size_t)n * 256 + zoffb) = o;
}

// ---------------- launch ----------------
extern "C" void kernel_launch(void* const* d_in, const int* in_sizes, int n_in,
                              void* d_out, int out_size, void* d_ws, size_t ws_size,
                              hipStream_t stream) {
  const float* h    = (const float*)d_in[0];
  const int*   src  = (const int*)d_in[1];
  const int*   dst  = (const int*)d_in[2];
  const float* Wq   = (const float*)d_in[3];
  const float* bq   = (const float*)d_in[4];
  const float* Wk   = (const float*)d_in[5];
  const float* bk   = (const float*)d_in[6];
  const float* Wm   = (const float*)d_in[7];
  const float* bm   = (const float*)d_in[8];
  const float* Wout = (const float*)d_in[9];
  const float* bout = (const float*)d_in[10];
  float* out = (float*)d_out;

  ushort* Abf    = (ushort*)d_ws;                    // NN*128 bf16
  ushort* Zbf    = Abf + (size_t)NN * 128;           // NN*384 bf16
  ushort* aggbf  = Zbf + (size_t)NN * 384;           // NN*128 bf16
  ushort* BTproj = aggbf + (size_t)NN * 128;         // 384*128
  ushort* BTout  = BTproj + 384 * 128;               // 128*128
  float*  bvec   = (float*)(BTout + 128 * 128);      // 384
  int* counts    = (int*)(bvec + 384);               // NN
  int* offsets   = counts + NN;                      // NN+1
  int* cursor    = offsets + NN + 1;                 // NN
  int* blockSums = cursor + NN;                      // 128
  int* csr_off   = blockSums + 128;                  // NE

  hipMemsetAsync(counts, 0, (size_t)NN * sizeof(int), stream);

  conv_h<<<6250, 256, 0, stream>>>(h, Abf);
  prep<<<256, 256, 0, stream>>>(Wq, Wk, Wm, bq, bk, bm, Wout, BTproj, BTout, bvec);
  mfma_gemm<0, 1><<<dim3(782, 3), 256, 0, stream>>>(Abf, BTproj, bvec, Zbf, NN, 384);

  hist_kernel<<<6250, 256, 0, stream>>>(dst, counts);
  scan_a<<<98, 256, 0, stream>>>(counts, offsets, blockSums, NN);
  scan_b<<<1, 128, 0, stream>>>(blockSums, 98);
  scan_c<<<391, 256, 0, stream>>>(offsets, blockSums, cursor, NN);
  scatter_part<<<3128, 256, 0, stream>>>(src, dst, cursor, csr_off);

  aggregate_fused<<<25000, 256, 0, stream>>>(Zbf, offsets, csr_off, aggbf);

  mfma_gemm<1, 0><<<dim3(782, 1), 256, 0, stream>>>(aggbf, BTout, bout, out, NN, 128);
}

// Round 5
// 368.260 us; speedup vs baseline: 2.5007x; 1.0143x over previous
//
#include <hip/hip_runtime.h>
#include <hip/hip_bf16.h>
#include <cstdint>
#include <cstddef>

#define NN 100000
#define NE 1600000
#define TAU 0.3f

typedef __attribute__((ext_vector_type(8))) short bf16x8;
typedef __attribute__((ext_vector_type(4))) float f32x4;

static __device__ __forceinline__ float b2f_hi(uint w) {
  return __uint_as_float(w & 0xffff0000u);
}
static __device__ __forceinline__ float b2f_lo(uint w) {
  return __uint_as_float(w << 16);
}
static __device__ __forceinline__ ushort f2b(float f) {
  uint x = __float_as_uint(f);
  return (ushort)((x + 0x7fffu + ((x >> 16) & 1u)) >> 16);
}

// ---------------- fused setup: conv_h (blocks 0..6249) + weight prep (6250..6505) ----------------
__global__ __launch_bounds__(256) void setup(
    const float* __restrict__ h, ushort* __restrict__ A,
    const float* __restrict__ Wq, const float* __restrict__ Wk, const float* __restrict__ Wm,
    const float* __restrict__ bq, const float* __restrict__ bk, const float* __restrict__ bm,
    const float* __restrict__ Wout,
    ushort* __restrict__ BTproj, ushort* __restrict__ BTout, float* __restrict__ bvec) {
  int b = blockIdx.x;
  if (b < 6250) {
    int i = b * 256 + threadIdx.x;   // exactly 1.6M threads -> 12.8M elems
    const float4* hv = (const float4*)h + (size_t)i * 2;
    float4 a = hv[0], c = hv[1];
    uint4 o;
    o.x = (uint)f2b(a.x) | ((uint)f2b(a.y) << 16);
    o.y = (uint)f2b(a.z) | ((uint)f2b(a.w) << 16);
    o.z = (uint)f2b(c.x) | ((uint)f2b(c.y) << 16);
    o.w = (uint)f2b(c.z) | ((uint)f2b(c.w) << 16);
    ((uint4*)A)[i] = o;
    return;
  }
  int id = (b - 6250) * 256 + threadIdx.x;   // 65536 threads
  if (id < 384 * 128) {
    int j = id >> 7, k = id & 127;
    int w = j >> 7, r = j & 127, hh = r >> 5, d = r & 31;
    const float* W = (w == 0) ? Wq : (w == 1) ? Wk : Wm;
    BTproj[id] = f2b(W[hh * 4096 + k * 32 + d]);
    if (k == 0) {
      const float* bb = (w == 0) ? bq : (w == 1) ? bk : bm;
      bvec[j] = bb[hh * 32 + d];
    }
  } else {
    int id2 = id - 384 * 128;                // 16384
    int c = id2 >> 7, k = id2 & 127;
    BTout[id2] = f2b(Wout[k * 128 + c]);
  }
}

// ---------------- MFMA GEMM: C[M][ncols] = A[M][128] * BT^T + bias ----------------
// A bf16 row-major [M][128], BT bf16 [ncols][128]. 128x128 tile, 4 waves of 64x64.
// Staging: global_load_lds width-16, linear LDS dest, pre-swizzled SOURCE addr (G21).
template <int RELU, int OUTBF>
__global__ __launch_bounds__(256) void mfma_gemm(
    const ushort* __restrict__ A, const ushort* __restrict__ BT,
    const float* __restrict__ bias, void* __restrict__ Cp, int M, int ncols) {
  __shared__ ushort As[128 * 128];   // 32 KB
  __shared__ ushort Bs[128 * 128];   // 32 KB

  int t = threadIdx.x;
  int rowBase = blockIdx.x * 128, colBase = blockIdx.y * 128;

#pragma unroll
  for (int i = 0; i < 8; i++) {
    int flat = t + i * 256;          // 2048 chunks of 16B
    int row = flat >> 4;
    int kb = (flat & 15) * 16;       // byte offset along K
    int soff = kb ^ ((row & 7) << 4);   // pre-swizzled source offset
    int ar = rowBase + row; if (ar >= M) ar = M - 1;   // clamp (results discarded)
    __builtin_amdgcn_global_load_lds(
        (const __attribute__((address_space(1))) uint32_t*)((const char*)A + (size_t)ar * 256 + soff),
        (__attribute__((address_space(3))) uint32_t*)((char*)As + row * 256 + kb), 16, 0, 0);
    __builtin_amdgcn_global_load_lds(
        (const __attribute__((address_space(1))) uint32_t*)((const char*)BT + (size_t)(colBase + row) * 256 + soff),
        (__attribute__((address_space(3))) uint32_t*)((char*)Bs + row * 256 + kb), 16, 0, 0);
  }
  __syncthreads();

  int wv = t >> 6, L = t & 63;
  int wrow = (wv >> 1) * 64, wcol = (wv & 1) * 64;
  int lr = L & 15;
  int lk = (L >> 4) * 16;            // byte offset of this lane's 8 bf16 within 64B k-step
  f32x4 acc[4][4] = {};

#pragma unroll
  for (int ks = 0; ks < 4; ks++) {
    bf16x8 a[4], b[4];
#pragma unroll
    for (int i = 0; i < 4; i++) {
      int row = wrow + i * 16 + lr;
      a[i] = *(const bf16x8*)((const char*)As + row * 256 + ((ks * 64 + lk) ^ ((row & 7) << 4)));
      int col = wcol + i * 16 + lr;
      b[i] = *(const bf16x8*)((const char*)Bs + col * 256 + ((ks * 64 + lk) ^ ((col & 7) << 4)));
    }
#pragma unroll
    for (int i = 0; i < 4; i++)
#pragma unroll
      for (int j = 0; j < 4; j++)
        acc[i][j] = __builtin_amdgcn_mfma_f32_16x16x32_bf16(a[i], b[j], acc[i][j], 0, 0, 0);
  }

  int rquad = (L >> 4) * 4;
#pragma unroll
  for (int j = 0; j < 4; j++) {
    int col = colBase + wcol + j * 16 + lr;
    float bs = bias[col];
#pragma unroll
    for (int i = 0; i < 4; i++) {
      int row0 = rowBase + wrow + i * 16 + rquad;
#pragma unroll
      for (int r = 0; r < 4; r++) {
        int row = row0 + r;
        if (row >= M) continue;
        float v = acc[i][j][r] + bs;
        if (RELU) v = fmaxf(v, 0.f);
        if (OUTBF) ((ushort*)Cp)[(size_t)row * ncols + col] = f2b(v);
        else       ((float*)Cp)[(size_t)row * ncols + col] = v;
      }
    }
  }
}

// ---------------- CSR build ----------------
__global__ __launch_bounds__(256) void hist_kernel(const int* __restrict__ dst,
                                                   int* __restrict__ counts) {
  int e = blockIdx.x * 256 + threadIdx.x;
  if (e < NE) atomicAdd(&counts[dst[e]], 1);
}

__global__ __launch_bounds__(256) void scan_a(const int* __restrict__ counts,
                                              int* __restrict__ offsets,
                                              int* __restrict__ blockSums, int n) {
  __shared__ int lds[256];
  int b = blockIdx.x, t = threadIdx.x;
  int base = b * 1024 + t * 4;
  int4 v = make_int4(0, 0, 0, 0);
  if (base < n) v = *(const int4*)&counts[base];
  int s1 = v.x + v.y, s2 = s1 + v.z, s3 = s2 + v.w;
  lds[t] = s3;
  __syncthreads();
  for (int dd = 1; dd < 256; dd <<= 1) {
    int x = (t >= dd) ? lds[t - dd] : 0;
    __syncthreads();
    lds[t] += x;
    __syncthreads();
  }
  int excl = (t > 0) ? lds[t - 1] : 0;
  if (base < n) {
    int4 o = make_int4(excl, excl + v.x, excl + s1, excl + s2);
    *(int4*)&offsets[base] = o;
  }
  if (t == 255) blockSums[b] = lds[255];
}

__global__ __launch_bounds__(128) void scan_b(int* __restrict__ blockSums, int nb) {
  __shared__ int lds[128];
  int t = threadIdx.x;
  lds[t] = (t < nb) ? blockSums[t] : 0;
  __syncthreads();
  for (int dd = 1; dd < 128; dd <<= 1) {
    int x = (t >= dd) ? lds[t - dd] : 0;
    __syncthreads();
    lds[t] += x;
    __syncthreads();
  }
  if (t < nb) blockSums[t] = (t > 0) ? lds[t - 1] : 0;
}

__global__ __launch_bounds__(256) void scan_c(int* __restrict__ offsets,
                                              const int* __restrict__ blockSums,
                                              int* __restrict__ cursor, int n) {
  int i = blockIdx.x * 256 + threadIdx.x;
  if (i < n) {
    int v = offsets[i] + blockSums[i >> 10];
    offsets[i] = v;
    cursor[i] = v;
  }
  if (i == 0) offsets[n] = NE;
}

// ---- XCD-partitioned scatter: csr payload = src row BYTE offset (src*768) ----
#define SC_CHUNK 4096
__global__ __launch_bounds__(256) void scatter_part(
    const int* __restrict__ src, const int* __restrict__ dst,
    int* __restrict__ cursor, int* __restrict__ csr_off) {
  int part = blockIdx.x & 7;
  int base = (blockIdx.x >> 3) * SC_CHUNK + threadIdx.x;
#pragma unroll
  for (int i = 0; i < SC_CHUNK / 256; i++) {
    int e = base + i * 256;
    if (e < NE) {
      int d = dst[e];
      if ((d >> 14) == part) {
        int pos = atomicAdd(&cursor[d], 1);
        csr_off[pos] = src[e] * 768;
      }
    }
  }
}

// ---------------- fused per-node attention + aggregation, 2 edges per wave ----------------
// wave per node; lane L: half = L>>5 handles edge (p + half); within half,
// lane l = L&31 covers head hh = l>>3, dims 4*(l&7)..+3 (uint2 = 8B of a 256B segment).
// Z row layout (bf16): [zq 0..127 | zk 128..255 | zm 256..383], 768 B/row
__global__ __launch_bounds__(256) void aggregate_fused2(
    const ushort* __restrict__ Z, const int* __restrict__ offsets,
    const int* __restrict__ csr_off, ushort* __restrict__ aggbf) {
  int wv = threadIdx.x >> 6, L = threadIdx.x & 63;
  int n = blockIdx.x * 4 + wv;
  if (n >= NN) return;
  int half = L >> 5, l = L & 31;
  int seg = (l >> 3) * 64 + (l & 7) * 8;   // byte offset within a 256B segment
  const char* ZB = (const char*)Z;
  int koff = 256 + seg;

  uint2 qw = *(const uint2*)(ZB + (size_t)n * 768 + seg);
  float q0 = b2f_lo(qw.x), q1 = b2f_hi(qw.x);
  float q2 = b2f_lo(qw.y), q3 = b2f_hi(qw.y);

  int start = offsets[n], end = offsets[n + 1];
  float den = 0.f, a0 = 0.f, a1 = 0.f, a2 = 0.f, a3 = 0.f;
  int p = start;

  // main loop: 4 edges per iteration, all valid, no predication
  for (; p + 4 <= end; p += 4) {
    int ad0 = csr_off[p + half] + koff;
    int ad1 = csr_off[p + 2 + half] + koff;
    uint2 kw0 = *(const uint2*)(ZB + ad0);
    uint2 mw0 = *(const uint2*)(ZB + ad0 + 256);
    uint2 kw1 = *(const uint2*)(ZB + ad1);
    uint2 mw1 = *(const uint2*)(ZB + ad1 + 256);

    float pd0 = fmaf(b2f_lo(kw0.x), q0,
                fmaf(b2f_hi(kw0.x), q1,
                fmaf(b2f_lo(kw0.y), q2, b2f_hi(kw0.y) * q3)));
    float pd1 = fmaf(b2f_lo(kw1.x), q0,
                fmaf(b2f_hi(kw1.x), q1,
                fmaf(b2f_lo(kw1.y), q2, b2f_hi(kw1.y) * q3)));
    pd0 += __shfl_xor(pd0, 1); pd1 += __shfl_xor(pd1, 1);
    pd0 += __shfl_xor(pd0, 2); pd1 += __shfl_xor(pd1, 2);
    pd0 += __shfl_xor(pd0, 4); pd1 += __shfl_xor(pd1, 4);
    float w0 = __expf(TAU * pd0);
    float w1 = __expf(TAU * pd1);
    den += w0 + w1;
    a0 = fmaf(b2f_lo(mw0.x), w0, a0); a1 = fmaf(b2f_hi(mw0.x), w0, a1);
    a2 = fmaf(b2f_lo(mw0.y), w0, a2); a3 = fmaf(b2f_hi(mw0.y), w0, a3);
    a0 = fmaf(b2f_lo(mw1.x), w1, a0); a1 = fmaf(b2f_hi(mw1.x), w1, a1);
    a2 = fmaf(b2f_lo(mw1.y), w1, a2); a3 = fmaf(b2f_hi(mw1.y), w1, a3);
  }
  // masked tail (< 4 edges)
  for (; p < end; p += 2) {
    int e = p + half;
    bool valid = e < end;
    int adr = csr_off[valid ? e : p] + koff;
    uint2 kw = *(const uint2*)(ZB + adr);
    uint2 mw = *(const uint2*)(ZB + adr + 256);
    float pd = fmaf(b2f_lo(kw.x), q0,
               fmaf(b2f_hi(kw.x), q1,
               fmaf(b2f_lo(kw.y), q2, b2f_hi(kw.y) * q3)));
    pd += __shfl_xor(pd, 1);
    pd += __shfl_xor(pd, 2);
    pd += __shfl_xor(pd, 4);
    float w = valid ? __expf(TAU * pd) : 0.f;
    den += w;
    a0 = fmaf(b2f_lo(mw.x), w, a0); a1 = fmaf(b2f_hi(mw.x), w, a1);
    a2 = fmaf(b2f_lo(mw.y), w, a2); a3 = fmaf(b2f_hi(mw.y), w, a3);
  }

  // combine the two halves
  den += __shfl_xor(den, 32);
  a0 += __shfl_xor(a0, 32);
  a1 += __shfl_xor(a1, 32);
  a2 += __shfl_xor(a2, 32);
  a3 += __shfl_xor(a3, 32);
  float inv = (den > 0.f) ? 1.0f / den : 0.f;
  if (half == 0) {
    uint2 o;
    o.x = (uint)f2b(a0 * inv) | ((uint)f2b(a1 * inv) << 16);
    o.y = (uint)f2b(a2 * inv) | ((uint)f2b(a3 * inv) << 16);
    *(uint2*)((char*)aggbf + (size_t)n * 256 + seg) = o;
  }
}

// ---------------- launch ----------------
extern "C" void kernel_launch(void* const* d_in, const int* in_sizes, int n_in,
                              void* d_out, int out_size, void* d_ws, size_t ws_size,
                              hipStream_t stream) {
  const float* h    = (const float*)d_in[0];
  const int*   src  = (const int*)d_in[1];
  const int*   dst  = (const int*)d_in[2];
  const float* Wq   = (const float*)d_in[3];
  const float* bq   = (const float*)d_in[4];
  const float* Wk   = (const float*)d_in[5];
  const float* bk   = (const float*)d_in[6];
  const float* Wm   = (const float*)d_in[7];
  const float* bm   = (const float*)d_in[8];
  const float* Wout = (const float*)d_in[9];
  const float* bout = (const float*)d_in[10];
  float* out = (float*)d_out;

  ushort* Abf    = (ushort*)d_ws;                    // NN*128 bf16
  ushort* Zbf    = Abf + (size_t)NN * 128;           // NN*384 bf16
  ushort* aggbf  = Zbf + (size_t)NN * 384;           // NN*128 bf16
  ushort* BTproj = aggbf + (size_t)NN * 128;         // 384*128
  ushort* BTout  = BTproj + 384 * 128;               // 128*128
  float*  bvec   = (float*)(BTout + 128 * 128);      // 384
  int* counts    = (int*)(bvec + 384);               // NN
  int* offsets   = counts + NN;                      // NN+1
  int* cursor    = offsets + NN + 1;                 // NN
  int* blockSums = cursor + NN;                      // 128
  int* csr_off   = blockSums + 128;                  // NE

  hipMemsetAsync(counts, 0, (size_t)NN * sizeof(int), stream);

  setup<<<6506, 256, 0, stream>>>(h, Abf, Wq, Wk, Wm, bq, bk, bm, Wout,
                                  BTproj, BTout, bvec);
  mfma_gemm<0, 1><<<dim3(782, 3), 256, 0, stream>>>(Abf, BTproj, bvec, Zbf, NN, 384);

  hist_kernel<<<6250, 256, 0, stream>>>(dst, counts);
  scan_a<<<98, 256, 0, stream>>>(counts, offsets, blockSums, NN);
  scan_b<<<1, 128, 0, stream>>>(blockSums, 98);
  scan_c<<<391, 256, 0, stream>>>(offsets, blockSums, cursor, NN);
  scatter_part<<<3128, 256, 0, stream>>>(src, dst, cursor, csr_off);

  aggregate_fused2<<<25000, 256, 0, stream>>>(Zbf, offsets, csr_off, aggbf);

  mfma_gemm<1, 0><<<dim3(782, 1), 256, 0, stream>>>(aggbf, BTout, bout, out, NN, 128);
}

// Round 7
// 324.654 us; speedup vs baseline: 2.8366x; 1.1343x over previous
//
#include <hip/hip_runtime.h>
#include <hip/hip_bf16.h>
#include <cstdint>
#include <cstddef>

#define NN 100000
#define NE 1600000
#define TAU 0.3f

typedef __attribute__((ext_vector_type(8))) short bf16x8;
typedef __attribute__((ext_vector_type(4))) float f32x4;

static __device__ __forceinline__ float b2f_hi(uint w) {
  return __uint_as_float(w & 0xffff0000u);
}
static __device__ __forceinline__ float b2f_lo(uint w) {
  return __uint_as_float(w << 16);
}
static __device__ __forceinline__ ushort f2b(float f) {
  uint x = __float_as_uint(f);
  return (ushort)((x + 0x7fffu + ((x >> 16) & 1u)) >> 16);
}
// sign-extended byte k of word w -> float
static __device__ __forceinline__ float i8f(uint w, int k) {
  return (float)((int)(w << (24 - 8 * k)) >> 24);
}

// ------- K1: hist (blocks 0..6249) + conv_h (6250..12499) + prep (12500..12755) -------
__global__ __launch_bounds__(256) void setup_hist(
    const float* __restrict__ h, ushort* __restrict__ A,
    const float* __restrict__ Wq, const float* __restrict__ Wk, const float* __restrict__ Wm,
    const float* __restrict__ bq, const float* __restrict__ bk, const float* __restrict__ bm,
    const float* __restrict__ Wout,
    ushort* __restrict__ BTproj, ushort* __restrict__ BTout, float* __restrict__ bvec,
    const int* __restrict__ dst, int* __restrict__ counts) {
  int b = blockIdx.x;
  if (b < 6250) {                       // histogram over dst
    int e = b * 256 + threadIdx.x;
    if (e < NE) atomicAdd(&counts[dst[e]], 1);
    return;
  }
  if (b < 12500) {                      // h f32 -> bf16
    int i = (b - 6250) * 256 + threadIdx.x;
    const float4* hv = (const float4*)h + (size_t)i * 2;
    float4 a = hv[0], c = hv[1];
    uint4 o;
    o.x = (uint)f2b(a.x) | ((uint)f2b(a.y) << 16);
    o.y = (uint)f2b(a.z) | ((uint)f2b(a.w) << 16);
    o.z = (uint)f2b(c.x) | ((uint)f2b(c.y) << 16);
    o.w = (uint)f2b(c.z) | ((uint)f2b(c.w) << 16);
    ((uint4*)A)[i] = o;
    return;
  }
  int id = (b - 12500) * 256 + threadIdx.x;   // weight prep, 65536 threads
  if (id < 384 * 128) {
    int j = id >> 7, k = id & 127;
    int w = j >> 7, r = j & 127, hh = r >> 5, d = r & 31;
    const float* W = (w == 0) ? Wq : (w == 1) ? Wk : Wm;
    BTproj[id] = f2b(W[hh * 4096 + k * 32 + d]);
    if (k == 0) {
      const float* bb = (w == 0) ? bq : (w == 1) ? bk : bm;
      bvec[j] = bb[hh * 32 + d];
    }
  } else {
    int id2 = id - 384 * 128;                // 16384
    int c = id2 >> 7, k = id2 & 127;
    BTout[id2] = f2b(Wout[k * 128 + c]);
  }
}

// ---------------- MFMA GEMM: C[M][ncols] = A[M][128] * BT^T + bias ----------------
template <int RELU, int OUTBF>
__global__ __launch_bounds__(256) void mfma_gemm(
    const ushort* __restrict__ A, const ushort* __restrict__ BT,
    const float* __restrict__ bias, void* __restrict__ Cp, int M, int ncols) {
  __shared__ ushort As[128 * 128];
  __shared__ ushort Bs[128 * 128];

  int t = threadIdx.x;
  int rowBase = blockIdx.x * 128, colBase = blockIdx.y * 128;

#pragma unroll
  for (int i = 0; i < 8; i++) {
    int flat = t + i * 256;
    int row = flat >> 4;
    int kb = (flat & 15) * 16;
    int soff = kb ^ ((row & 7) << 4);
    int ar = rowBase + row; if (ar >= M) ar = M - 1;
    __builtin_amdgcn_global_load_lds(
        (const __attribute__((address_space(1))) uint32_t*)((const char*)A + (size_t)ar * 256 + soff),
        (__attribute__((address_space(3))) uint32_t*)((char*)As + row * 256 + kb), 16, 0, 0);
    __builtin_amdgcn_global_load_lds(
        (const __attribute__((address_space(1))) uint32_t*)((const char*)BT + (size_t)(colBase + row) * 256 + soff),
        (__attribute__((address_space(3))) uint32_t*)((char*)Bs + row * 256 + kb), 16, 0, 0);
  }
  __syncthreads();

  int wv = t >> 6, L = t & 63;
  int wrow = (wv >> 1) * 64, wcol = (wv & 1) * 64;
  int lr = L & 15;
  int lk = (L >> 4) * 16;
  f32x4 acc[4][4] = {};

#pragma unroll
  for (int ks = 0; ks < 4; ks++) {
    bf16x8 a[4], b[4];
#pragma unroll
    for (int i = 0; i < 4; i++) {
      int row = wrow + i * 16 + lr;
      a[i] = *(const bf16x8*)((const char*)As + row * 256 + ((ks * 64 + lk) ^ ((row & 7) << 4)));
      int col = wcol + i * 16 + lr;
      b[i] = *(const bf16x8*)((const char*)Bs + col * 256 + ((ks * 64 + lk) ^ ((col & 7) << 4)));
    }
#pragma unroll
    for (int i = 0; i < 4; i++)
#pragma unroll
      for (int j = 0; j < 4; j++)
        acc[i][j] = __builtin_amdgcn_mfma_f32_16x16x32_bf16(a[i], b[j], acc[i][j], 0, 0, 0);
  }

  int rquad = (L >> 4) * 4;
#pragma unroll
  for (int j = 0; j < 4; j++) {
    int col = colBase + wcol + j * 16 + lr;
    float bs = bias[col];
#pragma unroll
    for (int i = 0; i < 4; i++) {
      int row0 = rowBase + wrow + i * 16 + rquad;
#pragma unroll
      for (int r = 0; r < 4; r++) {
        int row = row0 + r;
        if (row >= M) continue;
        float v = acc[i][j][r] + bs;
        if (RELU) v = fmaxf(v, 0.f);
        if (OUTBF) ((ushort*)Cp)[(size_t)row * ncols + col] = f2b(v);
        else       ((float*)Cp)[(size_t)row * ncols + col] = v;
      }
    }
  }
}

// ---------------- CSR scans ----------------
__global__ __launch_bounds__(256) void scan_a(const int* __restrict__ counts,
                                              int* __restrict__ offsets,
                                              int* __restrict__ blockSums, int n) {
  __shared__ int lds[256];
  int b = blockIdx.x, t = threadIdx.x;
  int base = b * 1024 + t * 4;
  int4 v = make_int4(0, 0, 0, 0);
  if (base < n) v = *(const int4*)&counts[base];
  int s1 = v.x + v.y, s2 = s1 + v.z, s3 = s2 + v.w;
  lds[t] = s3;
  __syncthreads();
  for (int dd = 1; dd < 256; dd <<= 1) {
    int x = (t >= dd) ? lds[t - dd] : 0;
    __syncthreads();
    lds[t] += x;
    __syncthreads();
  }
  int excl = (t > 0) ? lds[t - 1] : 0;
  if (base < n) {
    int4 o = make_int4(excl, excl + v.x, excl + s1, excl + s2);
    *(int4*)&offsets[base] = o;
  }
  if (t == 255) blockSums[b] = lds[255];
}

__global__ __launch_bounds__(128) void scan_b(int* __restrict__ blockSums, int nb) {
  __shared__ int lds[128];
  int t = threadIdx.x;
  lds[t] = (t < nb) ? blockSums[t] : 0;
  __syncthreads();
  for (int dd = 1; dd < 128; dd <<= 1) {
    int x = (t >= dd) ? lds[t - dd] : 0;
    __syncthreads();
    lds[t] += x;
    __syncthreads();
  }
  if (t < nb) blockSums[t] = (t > 0) ? lds[t - 1] : 0;
}

__global__ __launch_bounds__(256) void scan_c(int* __restrict__ offsets,
                                              const int* __restrict__ blockSums,
                                              int* __restrict__ cursor, int n) {
  int i = blockIdx.x * 256 + threadIdx.x;
  if (i < n) {
    int v = offsets[i] + blockSums[i >> 10];
    offsets[i] = v;
    cursor[i] = v;
  }
  if (i == 0) offsets[n] = NE;
}

// ------- K6: scatter (blocks 0..3127, XCD-partitioned) + bf16->int8 quant (3128..9377) -------
// csr payload = plain src row index.
// Zkm row (256B): unit u (16B) = [zk dims 8u..8u+7 int8 | zm dims 8u..8u+7 int8]
// scales[row] = (s_k, s_m) f32; q stored = round(v/s), v ~= q*s.
#define SC_CHUNK 4096
__global__ __launch_bounds__(256) void scatter_conv(
    const int* __restrict__ src, const int* __restrict__ dst,
    int* __restrict__ cursor, int* __restrict__ csr_src,
    const ushort* __restrict__ Zbf, char* __restrict__ Zkm,
    float2* __restrict__ scales) {
  int b = blockIdx.x;
  if (b < 3128) {
    int part = b & 7;
    int base = (b >> 3) * SC_CHUNK + threadIdx.x;
#pragma unroll
    for (int i = 0; i < SC_CHUNK / 256; i++) {
      int e = base + i * 256;
      if (e < NE) {
        int d = dst[e];
        if ((d >> 14) == part) {
          int pos = atomicAdd(&cursor[d], 1);
          csr_src[pos] = src[e];
        }
      }
    }
    return;
  }
  int g = (b - 3128) * 256 + threadIdx.x;   // 1.6M threads = 100K rows x 16 units
  int row = g >> 4, u = g & 15;
  const ushort* zr = Zbf + (size_t)row * 384;
  uint4 kk = *(const uint4*)(zr + 128 + u * 8);
  uint4 mm = *(const uint4*)(zr + 256 + u * 8);
  float kf[8] = {b2f_lo(kk.x), b2f_hi(kk.x), b2f_lo(kk.y), b2f_hi(kk.y),
                 b2f_lo(kk.z), b2f_hi(kk.z), b2f_lo(kk.w), b2f_hi(kk.w)};
  float mf[8] = {b2f_lo(mm.x), b2f_hi(mm.x), b2f_lo(mm.y), b2f_hi(mm.y),
                 b2f_lo(mm.z), b2f_hi(mm.z), b2f_lo(mm.w), b2f_hi(mm.w)};
  float mk = 0.f, mx = 0.f;
#pragma unroll
  for (int i = 0; i < 8; i++) { mk = fmaxf(mk, fabsf(kf[i])); mx = fmaxf(mx, fabsf(mf[i])); }
#pragma unroll
  for (int d = 1; d < 16; d <<= 1) {
    mk = fmaxf(mk, __shfl_xor(mk, d));
    mx = fmaxf(mx, __shfl_xor(mx, d));
  }
  mk = fmaxf(mk, 1e-20f); mx = fmaxf(mx, 1e-20f);
  float qk = 127.0f / mk, qm = 127.0f / mx;
  int q[16];
#pragma unroll
  for (int i = 0; i < 8; i++) {
    q[i] = __float2int_rn(kf[i] * qk) & 0xff;
    q[8 + i] = __float2int_rn(mf[i] * qm) & 0xff;
  }
  uint4 o;
  o.x = (uint)(q[0] | (q[1] << 8) | (q[2] << 16) | (q[3] << 24));
  o.y = (uint)(q[4] | (q[5] << 8) | (q[6] << 16) | (q[7] << 24));
  o.z = (uint)(q[8] | (q[9] << 8) | (q[10] << 16) | (q[11] << 24));
  o.w = (uint)(q[12] | (q[13] << 8) | (q[14] << 16) | (q[15] << 24));
  *(uint4*)(Zkm + (size_t)row * 256 + u * 16) = o;
  if (u == 0) scales[row] = make_float2(mk * (1.0f / 127.0f), mx * (1.0f / 127.0f));
}

// ---------------- fused attention + aggregation, int8 gathers, 4 edges/wave ----------------
// wave per node; lane L: quarter qt=L>>4 handles edge p+qt; l=L&15 covers dims 8l..8l+7,
// head = l>>2 (per-head dot reduce = shfl_xor 1,2). One uint4 gather covers zk+zm.
__global__ __launch_bounds__(256) void aggregate_q(
    const char* __restrict__ Zkm, const ushort* __restrict__ Zbf,
    const float2* __restrict__ scales,
    const int* __restrict__ offsets, const int* __restrict__ csr_src,
    ushort* __restrict__ aggbf) {
  int wv = threadIdx.x >> 6, L = threadIdx.x & 63;
  int n = blockIdx.x * 4 + wv;
  if (n >= NN) return;
  int qt = L >> 4, l = L & 15;
  int lb = l << 4;                         // byte offset within 256B row

  uint4 qw = *(const uint4*)((const char*)Zbf + (size_t)n * 768 + lb);  // zq dims 8l..8l+7
  float q0 = b2f_lo(qw.x), q1 = b2f_hi(qw.x), q2 = b2f_lo(qw.y), q3 = b2f_hi(qw.y);
  float q4 = b2f_lo(qw.z), q5 = b2f_hi(qw.z), q6 = b2f_lo(qw.w), q7 = b2f_hi(qw.w);

  int start = offsets[n], end = offsets[n + 1];
  float den = 0.f;
  float a0 = 0.f, a1 = 0.f, a2 = 0.f, a3 = 0.f, a4 = 0.f, a5 = 0.f, a6 = 0.f, a7 = 0.f;
  int p = start;

  for (; p + 8 <= end; p += 8) {
    int s0 = csr_src[p + qt];
    int s1 = csr_src[p + 4 + qt];
    uint4 v0 = *(const uint4*)(Zkm + ((size_t)s0 << 8) + lb);
    uint4 v1 = *(const uint4*)(Zkm + ((size_t)s1 << 8) + lb);
    float2 sc0 = scales[s0];
    float2 sc1 = scales[s1];

    float pd0 = i8f(v0.x, 0) * q0;
    pd0 = fmaf(i8f(v0.x, 1), q1, pd0); pd0 = fmaf(i8f(v0.x, 2), q2, pd0);
    pd0 = fmaf(i8f(v0.x, 3), q3, pd0); pd0 = fmaf(i8f(v0.y, 0), q4, pd0);
    pd0 = fmaf(i8f(v0.y, 1), q5, pd0); pd0 = fmaf(i8f(v0.y, 2), q6, pd0);
    pd0 = fmaf(i8f(v0.y, 3), q7, pd0);
    float pd1 = i8f(v1.x, 0) * q0;
    pd1 = fmaf(i8f(v1.x, 1), q1, pd1); pd1 = fmaf(i8f(v1.x, 2), q2, pd1);
    pd1 = fmaf(i8f(v1.x, 3), q3, pd1); pd1 = fmaf(i8f(v1.y, 0), q4, pd1);
    pd1 = fmaf(i8f(v1.y, 1), q5, pd1); pd1 = fmaf(i8f(v1.y, 2), q6, pd1);
    pd1 = fmaf(i8f(v1.y, 3), q7, pd1);

    pd0 += __shfl_xor(pd0, 1); pd1 += __shfl_xor(pd1, 1);
    pd0 += __shfl_xor(pd0, 2); pd1 += __shfl_xor(pd1, 2);
    float w0 = __expf(TAU * sc0.x * pd0);
    float w1 = __expf(TAU * sc1.x * pd1);
    den += w0 + w1;
    float wm0 = w0 * sc0.y, wm1 = w1 * sc1.y;

    a0 = fmaf(i8f(v0.z, 0), wm0, a0); a1 = fmaf(i8f(v0.z, 1), wm0, a1);
    a2 = fmaf(i8f(v0.z, 2), wm0, a2); a3 = fmaf(i8f(v0.z, 3), wm0, a3);
    a4 = fmaf(i8f(v0.w, 0), wm0, a4); a5 = fmaf(i8f(v0.w, 1), wm0, a5);
    a6 = fmaf(i8f(v0.w, 2), wm0, a6); a7 = fmaf(i8f(v0.w, 3), wm0, a7);
    a0 = fmaf(i8f(v1.z, 0), wm1, a0); a1 = fmaf(i8f(v1.z, 1), wm1, a1);
    a2 = fmaf(i8f(v1.z, 2), wm1, a2); a3 = fmaf(i8f(v1.z, 3), wm1, a3);
    a4 = fmaf(i8f(v1.w, 0), wm1, a4); a5 = fmaf(i8f(v1.w, 1), wm1, a5);
    a6 = fmaf(i8f(v1.w, 2), wm1, a6); a7 = fmaf(i8f(v1.w, 3), wm1, a7);
  }

  for (; p < end; p += 4) {               // masked tail, whole wave stays
    int e = p + qt;
    int idx = (e < end) ? e : (end - 1);
    int s0 = csr_src[idx];
    uint4 v = *(const uint4*)(Zkm + ((size_t)s0 << 8) + lb);
    float2 sc = scales[s0];
    float pd = i8f(v.x, 0) * q0;
    pd = fmaf(i8f(v.x, 1), q1, pd); pd = fmaf(i8f(v.x, 2), q2, pd);
    pd = fmaf(i8f(v.x, 3), q3, pd); pd = fmaf(i8f(v.y, 0), q4, pd);
    pd = fmaf(i8f(v.y, 1), q5, pd); pd = fmaf(i8f(v.y, 2), q6, pd);
    pd = fmaf(i8f(v.y, 3), q7, pd);
    pd += __shfl_xor(pd, 1);
    pd += __shfl_xor(pd, 2);
    float w = (e < end) ? __expf(TAU * sc.x * pd) : 0.f;
    den += w;
    float wm = w * sc.y;
    a0 = fmaf(i8f(v.z, 0), wm, a0); a1 = fmaf(i8f(v.z, 1), wm, a1);
    a2 = fmaf(i8f(v.z, 2), wm, a2); a3 = fmaf(i8f(v.z, 3), wm, a3);
    a4 = fmaf(i8f(v.w, 0), wm, a4); a5 = fmaf(i8f(v.w, 1), wm, a5);
    a6 = fmaf(i8f(v.w, 2), wm, a6); a7 = fmaf(i8f(v.w, 3), wm, a7);
  }

  // combine the four quarters (same l -> same dims/head)
  den += __shfl_xor(den, 16); den += __shfl_xor(den, 32);
  a0 += __shfl_xor(a0, 16); a0 += __shfl_xor(a0, 32);
  a1 += __shfl_xor(a1, 16); a1 += __shfl_xor(a1, 32);
  a2 += __shfl_xor(a2, 16); a2 += __shfl_xor(a2, 32);
  a3 += __shfl_xor(a3, 16); a3 += __shfl_xor(a3, 32);
  a4 += __shfl_xor(a4, 16); a4 += __shfl_xor(a4, 32);
  a5 += __shfl_xor(a5, 16); a5 += __shfl_xor(a5, 32);
  a6 += __shfl_xor(a6, 16); a6 += __shfl_xor(a6, 32);
  a7 += __shfl_xor(a7, 16); a7 += __shfl_xor(a7, 32);

  float inv = (den > 0.f) ? 1.0f / den : 0.f;
  if (qt == 0) {
    uint4 o;
    o.x = (uint)f2b(a0 * inv) | ((uint)f2b(a1 * inv) << 16);
    o.y = (uint)f2b(a2 * inv) | ((uint)f2b(a3 * inv) << 16);
    o.z = (uint)f2b(a4 * inv) | ((uint)f2b(a5 * inv) << 16);
    o.w = (uint)f2b(a6 * inv) | ((uint)f2b(a7 * inv) << 16);
    *(uint4*)((char*)aggbf + (size_t)n * 256 + lb) = o;
  }
}

// ---------------- launch ----------------
extern "C" void kernel_launch(void* const* d_in, const int* in_sizes, int n_in,
                              void* d_out, int out_size, void* d_ws, size_t ws_size,
                              hipStream_t stream) {
  const float* h    = (const float*)d_in[0];
  const int*   src  = (const int*)d_in[1];
  const int*   dst  = (const int*)d_in[2];
  const float* Wq   = (const float*)d_in[3];
  const float* bq   = (const float*)d_in[4];
  const float* Wk   = (const float*)d_in[5];
  const float* bk   = (const float*)d_in[6];
  const float* Wm   = (const float*)d_in[7];
  const float* bm   = (const float*)d_in[8];
  const float* Wout = (const float*)d_in[9];
  const float* bout = (const float*)d_in[10];
  float* out = (float*)d_out;

  char* base = (char*)d_ws;
  ushort* Abf    = (ushort*)base;                         // NN*128 bf16 (reused as Zkm)
  char*   Zkm    = base;                                  // NN*256B int8, overlaps Abf
  ushort* Zbf    = (ushort*)(base + 25600000);            // NN*384 bf16
  ushort* aggbf  = (ushort*)(base + 102400000);           // NN*128 bf16
  float2* scales = (float2*)(base + 128000000);           // NN float2 (800000 B)
  ushort* BTproj = (ushort*)(base + 128800000);           // 98304 B
  ushort* BTout  = (ushort*)(base + 128898304);           // 32768 B
  float*  bvec   = (float*)(base + 128931072);            // pad to 2048 B
  int* counts    = (int*)(base + 128933120);              // 400000 B
  int* offsets   = (int*)(base + 129333120);              // (NN+2)*4 = 400008 B
  int* cursor    = (int*)(base + 129733128);              // 400000 B
  int* blockSums = (int*)(base + 130133128);              // 512 B
  int* csr_src   = (int*)(base + 130133640);              // NE*4

  hipMemsetAsync(counts, 0, (size_t)NN * sizeof(int), stream);

  setup_hist<<<12756, 256, 0, stream>>>(h, Abf, Wq, Wk, Wm, bq, bk, bm, Wout,
                                        BTproj, BTout, bvec, dst, counts);
  scan_a<<<98, 256, 0, stream>>>(counts, offsets, blockSums, NN);
  scan_b<<<1, 128, 0, stream>>>(blockSums, 98);
  scan_c<<<391, 256, 0, stream>>>(offsets, blockSums, cursor, NN);

  mfma_gemm<0, 1><<<dim3(782, 3), 256, 0, stream>>>(Abf, BTproj, bvec, Zbf, NN, 384);

  scatter_conv<<<9378, 256, 0, stream>>>(src, dst, cursor, csr_src, Zbf, Zkm, scales);

  aggregate_q<<<25000, 256, 0, stream>>>(Zkm, Zbf, scales, offsets, csr_src, aggbf);

  mfma_gemm<1, 0><<<dim3(782, 1), 256, 0, stream>>>(aggbf, BTout, bout, out, NN, 128);
}